// Round 2
// baseline (507.620 us; speedup 1.0000x reference)
//
#include <hip/hip_runtime.h>
#include <stdint.h>

typedef __attribute__((ext_vector_type(8))) short bf16x8;
typedef __attribute__((ext_vector_type(4))) float f32x4;
typedef unsigned short u16;
typedef __attribute__((ext_vector_type(4))) unsigned short us4;
typedef __attribute__((ext_vector_type(8))) unsigned short us8;

#define NP 104    // xT node-dim stride (x transposed: [feat][node]); 2-way LDS conflicts only
#define FPD 136   // ag feat-dim stride ([node][feat]); 2-way conflicts only

__device__ __constant__ int c_RS[9] = {0, 17, 22, 27, 31, 36, 42, 48, 60};
__device__ __constant__ int c_RE[9] = {16, 21, 26, 30, 35, 41, 47, 59, 67};

__device__ __forceinline__ float b2f(u16 h) {
    union { unsigned int u; float f; } v;
    v.u = ((unsigned int)h) << 16;
    return v.f;
}
__device__ __forceinline__ u16 f2b(float f) {
    union { float f; unsigned int u; } v;
    v.f = f;
    unsigned int r = v.u + 0x7fffu + ((v.u >> 16) & 1u);  // RNE
    return (u16)(r >> 16);
}

// Prep: pad adj (f32 77x77) -> bf16 [80][96] (zeros beyond 77 annihilate pad-node
// garbage), and transpose W0..W3 (f32 [k][n]) -> bf16 WT[l][n][k] for direct
// B-fragment loads (8 contiguous K per lane).
__global__ void prep_kernel(const float* __restrict__ adj,
                            const float* __restrict__ W0, const float* __restrict__ W1,
                            const float* __restrict__ W2, const float* __restrict__ W3,
                            u16* __restrict__ adjp, u16* __restrict__ WT) {
    int id = blockIdx.x * 256 + threadIdx.x;  // grid = 256*256 = 65536
    if (id < 80 * 96) {
        int m = id / 96, k = id - m * 96;
        adjp[id] = (m < 77 && k < 77) ? f2b(adj[m * 77 + k]) : (u16)0;
    }
    {
        int l = id >> 14, r = id & 16383;
        int n = r >> 7, k = r & 127;
        const float* W = (l == 0) ? W0 : (l == 1) ? W1 : (l == 2) ? W2 : W3;
        WT[id] = f2b(W[k * 128 + n]);
    }
}

__global__ __launch_bounds__(256, 2) void gcn_kernel(
    const float* __restrict__ lm, const float* __restrict__ Wr,
    const float* __restrict__ b0, const float* __restrict__ b1,
    const float* __restrict__ b2, const float* __restrict__ b3,
    const float* __restrict__ gamma, const float* __restrict__ beta,
    const u16* __restrict__ adjp, const u16* __restrict__ WT,
    float* __restrict__ out) {
    __shared__ __align__(16) u16 xT[128 * NP];   // x^T [feat][node] bf16, nodes 0..95
    __shared__ __align__(16) u16 ag[80 * FPD];   // row-major [node][feat] bf16
    __shared__ float WrF[128];
    __shared__ float biasF[512];
    __shared__ float gamF[128], betF[128];
    __shared__ float scoreS[80], wtS[80], muS[80], rsS[80];

    const int t = threadIdx.x;
    const int lane = t & 63;
    const int w = t >> 6;        // wave 0..3; wave owns feat-tiles tn = {w, w+4}
    const int lo = lane & 15;
    const int qd = lane >> 4;
    const size_t pos = blockIdx.x;
    const float* lmp = lm + pos * (68 * 128);

    // ---- phase 0: stage small tensors (f32); zero xT; lm f32 -> bf16 into ag ----
    if (t < 128) {
        WrF[t] = Wr[t];
        gamF[t] = gamma[t];
        betF[t] = beta[t];
        biasF[t] = b0[t];
        biasF[128 + t] = b1[t];
        biasF[256 + t] = b2[t];
        biasF[384 + t] = b3[t];
    }
    for (int i = t; i < 128 * NP / 8; i += 256) ((uint4*)xT)[i] = make_uint4(0, 0, 0, 0);
    const float4* lmp4 = (const float4*)lmp;
    for (int c = t; c < 68 * 32; c += 256) {     // 32 float4-chunks per node
        int n = c >> 5, q = c & 31;
        float4 v = lmp4[c];
        us4 o;
        o[0] = f2b(v.x); o[1] = f2b(v.y); o[2] = f2b(v.z); o[3] = f2b(v.w);
        *(us4*)(&ag[n * FPD + q * 4]) = o;
    }
    __syncthreads();

    // ---- phase A2: LDS transpose ag -> xT cols 0..67 ----
    for (int c = t; c < 68 * 16; c += 256) {
        int d8 = c / 68, n = c - d8 * 68;
        us8 v = *(const us8*)(&ag[n * FPD + d8 * 8]);
#pragma unroll
        for (int j = 0; j < 8; j++) xT[(d8 * 8 + j) * NP + n] = v[j];
    }
    // ---- phase B1: region-pool scores (br is a constant shift -> cancels in softmax) ----
    if (t < 68) {
        float s = 0.f;
        for (int d8 = 0; d8 < 16; d8++) {
            us8 v = *(const us8*)(&ag[t * FPD + d8 * 8]);
#pragma unroll
            for (int j = 0; j < 8; j++) s += b2f(v[j]) * WrF[d8 * 8 + j];
        }
        scoreS[t] = s;
    }
    __syncthreads();

    // ---- phase B2: per-region softmax weights ----
    if (t < 9) {
        int s0 = c_RS[t], e0 = c_RE[t];
        float mx = -3e38f;
        for (int i = s0; i <= e0; i++) mx = fmaxf(mx, scoreS[i]);
        float sum = 0.f;
        for (int i = s0; i <= e0; i++) sum += __expf(scoreS[i] - mx);
        float inv = 1.f / sum;
        for (int i = s0; i <= e0; i++) wtS[i] = __expf(scoreS[i] - mx) * inv;
    }
    __syncthreads();

    // ---- phase B3: pooled global nodes -> xT cols 68..76 ----
    for (int c = t; c < 9 * 128; c += 256) {
        int r = c >> 7, d = c & 127;
        int s0 = c_RS[r], e0 = c_RE[r];
        float g = 0.f;
        for (int n = s0; n <= e0; n++) g += wtS[n] * b2f(ag[n * FPD + d]);
        xT[d * NP + 68 + r] = f2b(g);
    }
    __syncthreads();

    // ---- 4-layer GCN: agg = adj@x (MFMA), out = relu(agg@W + b) [+ x] ----
    for (int l = 0; l < 4; l++) {
        f32x4 acc[5][2];
#pragma unroll
        for (int a = 0; a < 5; a++)
#pragma unroll
            for (int j = 0; j < 2; j++)
#pragma unroll
                for (int r = 0; r < 4; r++) acc[a][j][r] = 0.f;
        // step 1: agg = adjp(80x96) @ x(96x128); A from global (L1/L2-hot), B from xT
#pragma unroll
        for (int ks = 0; ks < 3; ks++) {
            bf16x8 bA[5], bB[2];
#pragma unroll
            for (int tm = 0; tm < 5; tm++)
                bA[tm] = *(const bf16x8*)(adjp + (tm * 16 + lo) * 96 + ks * 32 + qd * 8);
#pragma unroll
            for (int j = 0; j < 2; j++) {
                int tn = w + 4 * j;
                bB[j] = *(const bf16x8*)(&xT[(tn * 16 + lo) * NP + ks * 32 + qd * 8]);
            }
#pragma unroll
            for (int tm = 0; tm < 5; tm++)
#pragma unroll
                for (int j = 0; j < 2; j++)
                    acc[tm][j] = __builtin_amdgcn_mfma_f32_16x16x32_bf16(bA[tm], bB[j], acc[tm][j], 0, 0, 0);
        }
        // C layout (m89): col = lane&15, row = qd*4 + reg -> write agg row-major
#pragma unroll
        for (int tm = 0; tm < 5; tm++)
#pragma unroll
            for (int j = 0; j < 2; j++) {
                int col = (w + 4 * j) * 16 + lo;
#pragma unroll
                for (int r = 0; r < 4; r++) {
                    int row = tm * 16 + qd * 4 + r;
                    ag[row * FPD + col] = f2b(acc[tm][j][r]);
                }
            }
        __syncthreads();

        // step 2: out = agg(80x128) @ W(128x128); A from ag, B from WT (global)
#pragma unroll
        for (int a = 0; a < 5; a++)
#pragma unroll
            for (int j = 0; j < 2; j++)
#pragma unroll
                for (int r = 0; r < 4; r++) acc[a][j][r] = 0.f;
        const u16* WTl = WT + l * 16384;
#pragma unroll
        for (int ks = 0; ks < 4; ks++) {
            bf16x8 aF[5], bW[2];
#pragma unroll
            for (int tm = 0; tm < 5; tm++)
                aF[tm] = *(const bf16x8*)(&ag[(tm * 16 + lo) * FPD + ks * 32 + qd * 8]);
#pragma unroll
            for (int j = 0; j < 2; j++) {
                int tn = w + 4 * j;
                bW[j] = *(const bf16x8*)(WTl + (tn * 16 + lo) * 128 + ks * 32 + qd * 8);
            }
#pragma unroll
            for (int tm = 0; tm < 5; tm++)
#pragma unroll
                for (int j = 0; j < 2; j++)
                    acc[tm][j] = __builtin_amdgcn_mfma_f32_16x16x32_bf16(aF[tm], bW[j], acc[tm][j], 0, 0, 0);
        }
        if (l == 3) __syncthreads();  // all waves done reading ag before overwrite
        // epilogue: bias + relu (+ residual = current x from xT), write next x
#pragma unroll
        for (int j = 0; j < 2; j++) {
            int col = (w + 4 * j) * 16 + lo;
            float bv = biasF[l * 128 + col];
#pragma unroll
            for (int tm = 0; tm < 5; tm++)
#pragma unroll
                for (int r = 0; r < 4; r++) {
                    int row = tm * 16 + qd * 4 + r;
                    float v = fmaxf(acc[tm][j][r] + bv, 0.f);
                    if (l < 3) {
                        v += b2f(xT[col * NP + row]);  // residual == current x
                        xT[col * NP + row] = f2b(v);
                    } else {
                        ag[row * FPD + col] = f2b(v);  // final: row-major for LN+store
                    }
                }
        }
        __syncthreads();
    }

    // ---- LayerNorm stats (one node per thread) ----
    if (t < 77) {
        float s = 0.f, ss = 0.f;
        for (int d = 0; d < 128; d += 2) {
            uint32_t v = *(const uint32_t*)(&ag[t * FPD + d]);
            float a = b2f((u16)(v & 0xffff)), b = b2f((u16)(v >> 16));
            s += a + b;
            ss += a * a + b * b;
        }
        float mu = s * (1.f / 128.f);
        float var = ss * (1.f / 128.f) - mu * mu;
        muS[t] = mu;
        rsS[t] = rsqrtf(var + 1e-5f);
    }
    __syncthreads();

    // ---- normalize + coalesced f32 store (out[pos][node][feat], 16B/lane) ----
    float* outp = out + pos * 9856;
    for (int c = t; c < 77 * 32; c += 256) {
        int n = c >> 5, q = c & 31;
        us4 v = *(const us4*)(&ag[n * FPD + q * 4]);
        float mu = muS[n], rs = rsS[n];
        float4 o;
        int d = q * 4;
        o.x = (b2f(v[0]) - mu) * rs * gamF[d + 0] + betF[d + 0];
        o.y = (b2f(v[1]) - mu) * rs * gamF[d + 1] + betF[d + 1];
        o.z = (b2f(v[2]) - mu) * rs * gamF[d + 2] + betF[d + 2];
        o.w = (b2f(v[3]) - mu) * rs * gamF[d + 3] + betF[d + 3];
        *(float4*)(outp + n * 128 + d) = o;
    }
}

extern "C" void kernel_launch(void* const* d_in, const int* in_sizes, int n_in,
                              void* d_out, int out_size, void* d_ws, size_t ws_size,
                              hipStream_t stream) {
    const float* lm = (const float*)d_in[0];
    const float* adj = (const float*)d_in[1];
    const float* Wr = (const float*)d_in[2];
    // d_in[3] = br: constant shift inside softmax -> cancels, unused
    const float* W0 = (const float*)d_in[4];
    const float* b0 = (const float*)d_in[5];
    const float* W1 = (const float*)d_in[6];
    const float* b1 = (const float*)d_in[7];
    const float* W2 = (const float*)d_in[8];
    const float* b2 = (const float*)d_in[9];
    const float* W3 = (const float*)d_in[10];
    const float* b3 = (const float*)d_in[11];
    const float* gamma = (const float*)d_in[12];
    const float* beta = (const float*)d_in[13];

    u16* adjp = (u16*)d_ws;                            // 80*96*2 = 15,360 B
    u16* WT = (u16*)((char*)d_ws + 80 * 96 * 2);       // 4*128*128*2 = 131,072 B

    prep_kernel<<<256, 256, 0, stream>>>(adj, W0, W1, W2, W3, adjp, WT);
    gcn_kernel<<<4096, 256, 0, stream>>>(lm, Wr, b0, b1, b2, b3, gamma, beta,
                                         adjp, WT, (float*)d_out);
}